// Round 6
// baseline (345.673 us; speedup 1.0000x reference)
//
#include <hip/hip_runtime.h>
#include <hip/hip_bf16.h>
#include <hip/hip_fp16.h>

// ScannedRNN (GRU with resets), T=512 B=256 H=INP=256, MI355X gfx950.
//
// Round 6:
//  - amdgpu_waves_per_eu(2,2): true 256 unified regs/wave (the round-4/5
//    cap at 128 caused AGPR shuffles / scratch spill).
//  - Weights: r,z (both hid-tiles) + n/ht0 in 160 VGPRs; n/ht1 in 64 KiB LDS.
//  - sigma K-layout: h stored as (hid,hid+16) pairs -> 4 ds_write_b32 per
//    thread/step via v_cvt_pk_bf16_f32; w_hh K-dim repacked with sigma^-1.
//  - Delayed out-stores (one step) so gi vmcnt-retire never drains stores.
//  - acc init = gi (r,z) / b_hh (n) via MFMA C-in.
//  - Unchanged: gi[t][btile][g][wid][lane][ht*4+j] f16 blocks (WG-private),
//    one lgkm-only barrier/step, 1-step gi prefetch, exact reset lookback.

#define T_LEN 512
#define BATCH 256
#define HID   256

typedef __attribute__((ext_vector_type(8))) short s16x8;          // 8 bf16
typedef __attribute__((ext_vector_type(8))) unsigned short u16x8; // 8 f16
typedef __attribute__((ext_vector_type(4))) float fx4;            // 4 f32 acc

#define MFMA16 __builtin_amdgcn_mfma_f32_16x16x32_bf16
#define GATE_STRIDE 4096u
#define BLK_STRIDE  12288u
#define T_STRIDE    196608u

__device__ __forceinline__ unsigned short f2bf(float f) {
  union { float f; unsigned u; } v; v.f = f;
  unsigned r = v.u + 0x7fffu + ((v.u >> 16) & 1u);   // RNE
  return (unsigned short)(r >> 16);
}

__device__ __forceinline__ unsigned cvt_pk_bf16(float lo, float hi) {
  unsigned r;
  asm("v_cvt_pk_bf16_f32 %0, %1, %2" : "=v"(r) : "v"(lo), "v"(hi));
  return r;
}

__device__ __forceinline__ s16x8 pack8(float4 a, float4 b) {   // natural K
  s16x8 f;
  f[0] = (short)f2bf(a.x); f[1] = (short)f2bf(a.y);
  f[2] = (short)f2bf(a.z); f[3] = (short)f2bf(a.w);
  f[4] = (short)f2bf(b.x); f[5] = (short)f2bf(b.y);
  f[6] = (short)f2bf(b.z); f[7] = (short)f2bf(b.w);
  return f;
}

__device__ __forceinline__ s16x8 pack8i(float4 a, float4 b) {  // sigma K (interleave)
  s16x8 f;
  f[0] = (short)f2bf(a.x); f[1] = (short)f2bf(b.x);
  f[2] = (short)f2bf(a.y); f[3] = (short)f2bf(b.y);
  f[4] = (short)f2bf(a.z); f[5] = (short)f2bf(b.z);
  f[6] = (short)f2bf(a.w); f[7] = (short)f2bf(b.w);
  return f;
}

// 768x256 f32 weights -> bf16 MFMA B-fragments.
// wr[0]=r/ht0 wr[1]=r/ht1 wr[2]=z/ht0 wr[3]=z/ht1 wr[4]=n/ht0 (160 VGPR)
// Wl2 (64 KiB LDS): n/ht1, lines [wv][s8][lane]*16B.
// SIGMA: fragment elem i of k-group (s8,kgrp) <- W[row][s8*32+kgrp*4+(i>>1)+(i&1)*16]
template<bool SIGMA>
__device__ __forceinline__ void load_weights(const float* __restrict__ W,
                                             s16x8 (&wr)[5][8], char* Wl2,
                                             int tid, int wid, int col, int kgrp) {
#pragma unroll
  for (int g = 0; g < 3; ++g)
#pragma unroll
    for (int ht = 0; ht < 2; ++ht) {
      if (g == 2 && ht == 1) continue;
      int row = g * 256 + (wid * 2 + ht) * 16 + col;
#pragma unroll
      for (int s8 = 0; s8 < 8; ++s8) {
        if (SIGMA) {
          const float* pa = W + row * 256 + s8 * 32 + kgrp * 4;
          wr[g * 2 + ht][s8] = pack8i(*(const float4*)pa, *(const float4*)(pa + 16));
        } else {
          const float* pa = W + row * 256 + s8 * 32 + kgrp * 8;
          wr[g * 2 + ht][s8] = pack8(*(const float4*)pa, *(const float4*)(pa + 4));
        }
      }
    }
#pragma unroll
  for (int q = 0; q < 8; ++q) {
    int li = tid + q * 512;             // 4096 lines of 16B
    int wv = li >> 9, s8 = (li >> 6) & 7, l = li & 63;
    int row = 512 + (wv * 2 + 1) * 16 + (l & 15);
    s16x8 line;
    if (SIGMA) {
      const float* pa = W + row * 256 + s8 * 32 + (l >> 4) * 4;
      line = pack8i(*(const float4*)pa, *(const float4*)(pa + 16));
    } else {
      const float* pa = W + row * 256 + s8 * 32 + (l >> 4) * 8;
      line = pack8(*(const float4*)pa, *(const float4*)(pa + 4));
    }
    *(s16x8*)(Wl2 + li * 16) = line;
  }
}

__device__ __forceinline__ void soft_barrier() {
  asm volatile("s_waitcnt lgkmcnt(0)" ::: "memory");
  __builtin_amdgcn_s_barrier();
  __builtin_amdgcn_sched_barrier(0);
  asm volatile("" ::: "memory");
}

// ---------------- Kernel A: input projection -> gi (f16) ----------------
__global__ void __launch_bounds__(512)
__attribute__((amdgpu_waves_per_eu(2, 2)))
gi_proj_kernel(const float* __restrict__ X, const float* __restrict__ w_ih,
               const float* __restrict__ b_ih, const float* __restrict__ b_hh,
               __half* __restrict__ gi) {
  __shared__ __align__(16) char Wl2[65536];
  __shared__ __align__(16) char Ald[2][8192];

  const int tid = threadIdx.x;
  const int wid = tid >> 6, lane = tid & 63;
  const int col = lane & 15, kgrp = lane >> 4;

  s16x8 wr[5][8];
  load_weights<false>(X ? w_ih : w_ih, wr, Wl2, tid, wid, col, kgrp);

  float bias[2][3];
#pragma unroll
  for (int ht = 0; ht < 2; ++ht) {
    int gb = (wid * 2 + ht) * 16 + col;
    bias[ht][0] = b_ih[gb]       + b_hh[gb];
    bias[ht][1] = b_ih[256 + gb] + b_hh[256 + gb];
    bias[ht][2] = b_ih[512 + gb];     // n: b_hh applied inside r*( ) in scan
  }

  const int srow = tid >> 5, sk = (tid & 31) * 8;
  const unsigned sbyte = ((unsigned)(srow * 512 + sk * 2)) ^ ((unsigned)(srow & 7) << 4);

  float4 xc0 = *(const float4*)(X + (size_t)(blockIdx.x * 16 + srow) * 256 + sk);
  float4 xc1 = *(const float4*)(X + (size_t)(blockIdx.x * 16 + srow) * 256 + sk + 4);

  int parity = 0;
  for (int chunk = blockIdx.x; chunk < (T_LEN * BATCH) / 16; chunk += 256) {
    char* ab = Ald[parity];
    {
      uint4 v;
      v.x = cvt_pk_bf16(xc0.x, xc0.y);
      v.y = cvt_pk_bf16(xc0.z, xc0.w);
      v.z = cvt_pk_bf16(xc1.x, xc1.y);
      v.w = cvt_pk_bf16(xc1.z, xc1.w);
      *(uint4*)(ab + sbyte) = v;
    }
    int nchunk = chunk + 256;
    if (nchunk < (T_LEN * BATCH) / 16) {
      xc0 = *(const float4*)(X + (size_t)(nchunk * 16 + srow) * 256 + sk);
      xc1 = *(const float4*)(X + (size_t)(nchunk * 16 + srow) * 256 + sk + 4);
    }
    soft_barrier();

    fx4 acc[2][3];
#pragma unroll
    for (int ht = 0; ht < 2; ++ht)
#pragma unroll
      for (int g = 0; g < 3; ++g)
#pragma unroll
        for (int j = 0; j < 4; ++j)
          acc[ht][g][j] = bias[ht][g];        // bias via MFMA C-in

#pragma unroll
    for (int s8 = 0; s8 < 8; ++s8) {
      unsigned aoff = ((unsigned)(col * 512 + (s8 * 32 + kgrp * 8) * 2)) ^
                      ((unsigned)(col & 7) << 4);
      s16x8 af = *(const s16x8*)(ab + aoff);
      s16x8 w2 = *(const s16x8*)(Wl2 + ((wid * 8 + s8) * 64 + lane) * 16);
      acc[0][0] = MFMA16(af, wr[0][s8], acc[0][0], 0, 0, 0);
      acc[1][0] = MFMA16(af, wr[1][s8], acc[1][0], 0, 0, 0);
      acc[0][1] = MFMA16(af, wr[2][s8], acc[0][1], 0, 0, 0);
      acc[1][1] = MFMA16(af, wr[3][s8], acc[1][1], 0, 0, 0);
      acc[0][2] = MFMA16(af, wr[4][s8], acc[0][2], 0, 0, 0);
      acc[1][2] = MFMA16(af, w2, acc[1][2], 0, 0, 0);
    }

    __half* gb = gi + (size_t)chunk * BLK_STRIDE + (unsigned)(wid * 64 + lane) * 8;
#pragma unroll
    for (int g = 0; g < 3; ++g) {
      u16x8 o;
#pragma unroll
      for (int j = 0; j < 4; ++j) {
        o[j]     = __half_as_ushort(__float2half(acc[0][g][j]));
        o[4 + j] = __half_as_ushort(__float2half(acc[1][g][j]));
      }
      *(u16x8*)(gb + g * GATE_STRIDE) = o;
    }
    parity ^= 1;
  }
}

// ---------------- Kernel B: chunked GRU scan ----------------
__global__ void __launch_bounds__(512)
__attribute__((amdgpu_waves_per_eu(2, 2)))
gru_scan_kernel(const float* __restrict__ carry, const __half* __restrict__ gi,
                const int* __restrict__ resets, const float* __restrict__ w_hh,
                const float* __restrict__ b_hh, float* __restrict__ out) {
  __shared__ __align__(16) char Wl2[65536];
  __shared__ __align__(16) char Ald[2][8192];   // h bf16 A-tile (sigma K), dbuf
  __shared__ int lastreset[16];

  const int tid = threadIdx.x;
  const int wid = tid >> 6, lane = tid & 63;
  const int col = lane & 15, kgrp = lane >> 4;
  const int bid = blockIdx.x;
  const int bt = bid & 15, c = bid >> 4;
  const int b0 = bt * 16, t0 = c * 32, t1 = t0 + 32;
  const int hid0 = wid * 32 + col;              // wave owns hid0, hid0+16

  s16x8 wr[5][8];
  load_weights<true>(w_hh, wr, Wl2, tid, wid, col, kgrp);
  const float bhhn0 = b_hh[512 + hid0], bhhn1 = b_hh[512 + hid0 + 16];

  // ---- exact scan start ----
  int s, useCarry;
  if (c == 0) {
    s = 0; useCarry = 1;
  } else {
    if (tid < 16) lastreset[tid] = -1;
    for (int base = t0 - 32;; base -= 32) {
      __syncthreads();
      int tt = base + (tid >> 4);
      if (tt >= 0 && tt < t0) {
        if (resets[tt * BATCH + b0 + (tid & 15)] != 0)
          atomicMax(&lastreset[tid & 15], tt);
      }
      __syncthreads();
      int mn = t0, all = 1;
#pragma unroll
      for (int i = 0; i < 16; ++i) {
        int v = lastreset[i];
        all &= (v >= 0) ? 1 : 0;
        mn = min(mn, v < 0 ? t0 : v);
      }
      if (all) { s = mn; useCarry = 0; break; }
      if (base <= 0) { s = 0; useCarry = 1; break; }
    }
  }

  // ---- init state at t=s into Ald[0] (sigma layout: pairs (hid,hid+16)) ----
  {
    int row = tid >> 5, k0 = (tid & 31) * 8;
    int tile = k0 >> 5, colb = (k0 >> 1) & 15;
    int rst = resets[s * BATCH + b0 + row];
    float4 va = {0.f, 0.f, 0.f, 0.f}, vb = va;
    if (useCarry && !rst) {
      va = *(const float4*)(carry + (size_t)(b0 + row) * HID + tile * 32 + colb);
      vb = *(const float4*)(carry + (size_t)(b0 + row) * HID + tile * 32 + colb + 16);
    }
    uint4 u;
    u.x = cvt_pk_bf16(va.x, vb.x);
    u.y = cvt_pk_bf16(va.y, vb.y);
    u.z = cvt_pk_bf16(va.z, vb.z);
    u.w = cvt_pk_bf16(va.w, vb.w);
    unsigned byteoff = ((unsigned)(row * 512 + k0 * 2)) ^ ((unsigned)(row & 7) << 4);
    *(uint4*)(Ald[0] + byteoff) = u;
  }
  float hprev[2][4];
#pragma unroll
  for (int ht = 0; ht < 2; ++ht)
#pragma unroll
    for (int j = 0; j < 4; ++j) {
      int b = kgrp * 4 + j;
      int rst = resets[s * BATCH + b0 + b];
      float hv = 0.f;
      if (useCarry && !rst) hv = carry[(size_t)(b0 + b) * HID + hid0 + ht * 16];
      hprev[ht][j] = hv;
    }
  __syncthreads();

  // ---- pipelined scan ----
  const __half* gp = gi + (size_t)(s * 16 + bt) * BLK_STRIDE + (unsigned)(wid * 64 + lane) * 8;
  const int* rbase = resets + b0 + kgrp * 4;

  u16x8 gP0 = *(const u16x8*)(gp);
  u16x8 gP1 = *(const u16x8*)(gp + GATE_STRIDE);
  u16x8 gP2 = *(const u16x8*)(gp + 2 * GATE_STRIDE);
  int4 rnC = *(const int4*)(rbase + (size_t)((s + 1 < T_LEN) ? s + 1 : T_LEN - 1) * BATCH);

  float* opc = out + 65536 + ((size_t)s * BATCH + b0 + kgrp * 4) * HID + hid0;
  float* opf = opc;
  float hout[2][4] = {{0.f, 0.f, 0.f, 0.f}, {0.f, 0.f, 0.f, 0.f}};

  for (int t = s; t < t1; ++t) {
    // (1) VMEM loads for t+1 FIRST (their retire must not wait on stores)
    const __half* gq = gp + ((t + 1 < t1) ? T_STRIDE : 0u);
    u16x8 gN0 = *(const u16x8*)(gq);
    u16x8 gN1 = *(const u16x8*)(gq + GATE_STRIDE);
    u16x8 gN2 = *(const u16x8*)(gq + 2 * GATE_STRIDE);
    int tn = (t + 2 < T_LEN) ? t + 2 : T_LEN - 1;
    int4 rnN = *(const int4*)(rbase + (size_t)tn * BATCH);

    // (2) delayed flush of step t-1's outputs
    if (t > s && t - 1 >= t0) {
#pragma unroll
      for (int j = 0; j < 4; ++j) {
        __builtin_nontemporal_store(hout[0][j], opf + j * HID);
        __builtin_nontemporal_store(hout[1][j], opf + j * HID + 16);
      }
    }

    // (3) acc init: r,z from gi (C-in), n from b_hh
    fx4 a00, a10, a01, a11, a02, a12;
#pragma unroll
    for (int j = 0; j < 4; ++j) {
      a00[j] = __half2float(__ushort_as_half(gP0[j]));
      a10[j] = __half2float(__ushort_as_half(gP0[4 + j]));
      a01[j] = __half2float(__ushort_as_half(gP1[j]));
      a11[j] = __half2float(__ushort_as_half(gP1[4 + j]));
      a02[j] = bhhn0;
      a12[j] = bhhn1;
    }

    // (4) MFMA: 8 af reads + 8 w2 reads, 48 MFMA
    const char* ab = Ald[(t - s) & 1];
#pragma unroll
    for (int s8 = 0; s8 < 8; ++s8) {
      unsigned aoff = ((unsigned)(col * 512 + (s8 * 32 + kgrp * 8) * 2)) ^
                      ((unsigned)(col & 7) << 4);
      s16x8 af = *(const s16x8*)(ab + aoff);
      s16x8 w2 = *(const s16x8*)(Wl2 + ((wid * 8 + s8) * 64 + lane) * 16);
      a00 = MFMA16(af, wr[0][s8], a00, 0, 0, 0);
      a10 = MFMA16(af, wr[1][s8], a10, 0, 0, 0);
      a01 = MFMA16(af, wr[2][s8], a01, 0, 0, 0);
      a11 = MFMA16(af, wr[3][s8], a11, 0, 0, 0);
      a02 = MFMA16(af, wr[4][s8], a02, 0, 0, 0);
      a12 = MFMA16(af, w2, a12, 0, 0, 0);
    }

    // (5) gates + h write (paired b32, sigma layout)
    char* aw = (char*)Ald[((t - s) & 1) ^ 1];
    const bool lastT = (t + 1 >= T_LEN);
#pragma unroll
    for (int j = 0; j < 4; ++j) {
      int b = kgrp * 4 + j;
      int rj = (j == 0) ? rnC.x : (j == 1) ? rnC.y : (j == 2) ? rnC.z : rnC.w;
      if (lastT) rj = 0;

      float r0 = __builtin_amdgcn_rcpf(1.f + __expf(-a00[j]));
      float z0 = __builtin_amdgcn_rcpf(1.f + __expf(-a01[j]));
      float pn0 = __half2float(__ushort_as_half(gP2[j])) + r0 * a02[j];
      float n0 = 1.f - 2.f * __builtin_amdgcn_rcpf(1.f + __expf(2.f * pn0));
      float h0 = (1.f - z0) * n0 + z0 * hprev[0][j];

      float r1 = __builtin_amdgcn_rcpf(1.f + __expf(-a10[j]));
      float z1 = __builtin_amdgcn_rcpf(1.f + __expf(-a11[j]));
      float pn1 = __half2float(__ushort_as_half(gP2[4 + j])) + r1 * a12[j];
      float n1 = 1.f - 2.f * __builtin_amdgcn_rcpf(1.f + __expf(2.f * pn1));
      float h1 = (1.f - z1) * n1 + z1 * hprev[1][j];

      hout[0][j] = h0; hout[1][j] = h1;
      float hk0 = rj ? 0.f : h0;
      float hk1 = rj ? 0.f : h1;
      hprev[0][j] = hk0; hprev[1][j] = hk1;

      unsigned hw = cvt_pk_bf16(hk0, hk1);
      unsigned hoff = ((unsigned)(b * 512 + wid * 64 + col * 4)) ^
                      ((unsigned)(b & 7) << 4);
      *(unsigned*)(aw + hoff) = hw;
    }

    gP0 = gN0; gP1 = gN1; gP2 = gN2; rnC = rnN;
    gp = gq;
    opf = opc; opc += 65536;
    soft_barrier();   // lgkm drain only; gi prefetch + out stores stay in flight
  }

  // flush last step's outputs (t1-1 >= t0 always)
#pragma unroll
  for (int j = 0; j < 4; ++j) {
    __builtin_nontemporal_store(hout[0][j], opf + j * HID);
    __builtin_nontemporal_store(hout[1][j], opf + j * HID + 16);
  }

  if (c == 15) {       // h_final = h after t=511 (reset guarded off)
#pragma unroll
    for (int ht = 0; ht < 2; ++ht)
#pragma unroll
      for (int j = 0; j < 4; ++j)
        out[(size_t)(b0 + kgrp * 4 + j) * HID + hid0 + ht * 16] = hprev[ht][j];
  }
}

extern "C" void kernel_launch(void* const* d_in, const int* in_sizes, int n_in,
                              void* d_out, int out_size, void* d_ws, size_t ws_size,
                              hipStream_t stream) {
  const float* carry = (const float*)d_in[0];
  const float* X     = (const float*)d_in[1];
  const int*   rsts  = (const int*)d_in[2];
  const float* w_ih  = (const float*)d_in[3];
  const float* w_hh  = (const float*)d_in[4];
  const float* b_ih  = (const float*)d_in[5];
  const float* b_hh  = (const float*)d_in[6];
  float* out = (float*)d_out;

  const size_t gi_bytes = (size_t)T_LEN * BATCH * 3 * HID * sizeof(__half);  // 192 MiB
  if (ws_size < gi_bytes) return;
  __half* gi = (__half*)d_ws;

  gi_proj_kernel<<<256, 512, 0, stream>>>(X, w_ih, b_ih, b_hh, gi);
  gru_scan_kernel<<<256, 512, 0, stream>>>(carry, gi, rsts, w_hh, b_hh, out);
}

// Round 7
// 247.271 us; speedup vs baseline: 1.3979x; 1.3979x over previous
//
#include <hip/hip_runtime.h>
#include <hip/hip_bf16.h>
#include <hip/hip_fp16.h>

// ScannedRNN (GRU with resets), T=512 B=256 H=INP=256, MI355X gfx950.
//
// Round 7: round-4's spill-free allocation + round-6's VALU trims.
//  - Weights: r,z gates (both hid-tiles) = 128 regs -> fits the 128-AGPR
//    file exactly (MFMA reads B from AGPR directly). n-gate (both tiles)
//    in 128 KiB LDS, re-read per step (16 ds_read_b128/wave/step).
//  - sigma K-layout in the scan: h written as (hid,hid+16) pairs via
//    v_cvt_pk_bf16_f32 + ds_write_b32 (w_hh K-dim repacked to match).
//  - acc init via MFMA C-in (gi for r,z; b_hh for n).
//  - out stores issued AFTER next-step gi loads (FIFO: gi retire never
//    waits on stores), nontemporal.
//  - 512 thr (8 waves, 2/SIMD), one lgkm-only barrier per step, 1-step gi
//    prefetch, exact reset lookback, h fp32 in regs.

#define T_LEN 512
#define BATCH 256
#define HID   256

typedef __attribute__((ext_vector_type(8))) short s16x8;          // 8 bf16
typedef __attribute__((ext_vector_type(8))) unsigned short u16x8; // 8 f16
typedef __attribute__((ext_vector_type(4))) float fx4;            // 4 f32 acc

#define MFMA16 __builtin_amdgcn_mfma_f32_16x16x32_bf16
#define GATE_STRIDE 4096u              /* gi: 8 wid * 64 lane * 8 halves */
#define BLK_STRIDE  12288u             /* 3 gates */
#define T_STRIDE    196608u            /* 16 btiles */

__device__ __forceinline__ unsigned short f2bf(float f) {
  union { float f; unsigned u; } v; v.f = f;
  unsigned r = v.u + 0x7fffu + ((v.u >> 16) & 1u);   // RNE
  return (unsigned short)(r >> 16);
}

__device__ __forceinline__ unsigned cvt_pk_bf16(float lo, float hi) {
  unsigned r;
  asm("v_cvt_pk_bf16_f32 %0, %1, %2" : "=v"(r) : "v"(lo), "v"(hi));
  return r;
}

__device__ __forceinline__ s16x8 pack8(float4 a, float4 b) {   // natural K
  s16x8 f;
  f[0] = (short)f2bf(a.x); f[1] = (short)f2bf(a.y);
  f[2] = (short)f2bf(a.z); f[3] = (short)f2bf(a.w);
  f[4] = (short)f2bf(b.x); f[5] = (short)f2bf(b.y);
  f[6] = (short)f2bf(b.z); f[7] = (short)f2bf(b.w);
  return f;
}

__device__ __forceinline__ s16x8 pack8i(float4 a, float4 b) {  // sigma K
  s16x8 f;
  f[0] = (short)f2bf(a.x); f[1] = (short)f2bf(b.x);
  f[2] = (short)f2bf(a.y); f[3] = (short)f2bf(b.y);
  f[4] = (short)f2bf(a.z); f[5] = (short)f2bf(b.z);
  f[6] = (short)f2bf(a.w); f[7] = (short)f2bf(b.w);
  return f;
}

// 768x256 f32 weights -> bf16 MFMA B-fragments.
// wr[0]=r/ht0 wr[1]=r/ht1 wr[2]=z/ht0 wr[3]=z/ht1  (128 regs -> AGPR file)
// Wlds (128 KiB): n-gate both tiles, lines [(wid*2+ht)*8+s8][lane] * 16B.
// SIGMA: frag elem i of (s8,kgrp) <- W[row][s8*32 + kgrp*4 + (i>>1) + (i&1)*16]
template<bool SIGMA>
__device__ __forceinline__ void load_weights(const float* __restrict__ W,
                                             s16x8 (&wr)[4][8], char* Wlds,
                                             int tid, int wid, int col, int kgrp) {
#pragma unroll
  for (int g = 0; g < 2; ++g)
#pragma unroll
    for (int ht = 0; ht < 2; ++ht) {
      int row = g * 256 + (wid * 2 + ht) * 16 + col;
#pragma unroll
      for (int s8 = 0; s8 < 8; ++s8) {
        if (SIGMA) {
          const float* pa = W + row * 256 + s8 * 32 + kgrp * 4;
          wr[g * 2 + ht][s8] = pack8i(*(const float4*)pa, *(const float4*)(pa + 16));
        } else {
          const float* pa = W + row * 256 + s8 * 32 + kgrp * 8;
          wr[g * 2 + ht][s8] = pack8(*(const float4*)pa, *(const float4*)(pa + 4));
        }
      }
    }
#pragma unroll
  for (int q = 0; q < 16; ++q) {
    int li = tid + q * 512;             // 8192 lines of 16B (n-gate, all 256 rows)
    int wv = li >> 9, s8 = (li >> 6) & 7, l = li & 63;
    int row = 512 + wv * 16 + (l & 15);
    s16x8 line;
    if (SIGMA) {
      const float* pa = W + row * 256 + s8 * 32 + (l >> 4) * 4;
      line = pack8i(*(const float4*)pa, *(const float4*)(pa + 16));
    } else {
      const float* pa = W + row * 256 + s8 * 32 + (l >> 4) * 8;
      line = pack8(*(const float4*)pa, *(const float4*)(pa + 4));
    }
    *(s16x8*)(Wlds + li * 16) = line;
  }
}

__device__ __forceinline__ void soft_barrier() {
  asm volatile("s_waitcnt lgkmcnt(0)" ::: "memory");
  __builtin_amdgcn_s_barrier();
  __builtin_amdgcn_sched_barrier(0);
  asm volatile("" ::: "memory");
}

// ---------------- Kernel A: input projection -> gi (f16) ----------------
__global__ __launch_bounds__(512, 2) void gi_proj_kernel(
    const float* __restrict__ X, const float* __restrict__ w_ih,
    const float* __restrict__ b_ih, const float* __restrict__ b_hh,
    __half* __restrict__ gi) {
  __shared__ __align__(16) char Wlds[131072];
  __shared__ __align__(16) char Ald[2][8192];

  const int tid = threadIdx.x;
  const int wid = tid >> 6, lane = tid & 63;
  const int col = lane & 15, kgrp = lane >> 4;

  s16x8 wr[4][8];
  load_weights<false>(w_ih, wr, Wlds, tid, wid, col, kgrp);

  float bias[2][3];
#pragma unroll
  for (int ht = 0; ht < 2; ++ht) {
    int gb = (wid * 2 + ht) * 16 + col;
    bias[ht][0] = b_ih[gb]       + b_hh[gb];        // fold b_hh for r
    bias[ht][1] = b_ih[256 + gb] + b_hh[256 + gb];  // fold b_hh for z
    bias[ht][2] = b_ih[512 + gb];                   // n: b_hh inside r*( ) in scan
  }

  const int srow = tid >> 5, sk = (tid & 31) * 8;
  const unsigned sbyte = ((unsigned)(srow * 512 + sk * 2)) ^ ((unsigned)(srow & 7) << 4);

  float4 xc0 = *(const float4*)(X + (size_t)(blockIdx.x * 16 + srow) * 256 + sk);
  float4 xc1 = *(const float4*)(X + (size_t)(blockIdx.x * 16 + srow) * 256 + sk + 4);

  int parity = 0;
  for (int chunk = blockIdx.x; chunk < (T_LEN * BATCH) / 16; chunk += 256) {
    char* ab = Ald[parity];
    {
      uint4 v;
      v.x = cvt_pk_bf16(xc0.x, xc0.y);
      v.y = cvt_pk_bf16(xc0.z, xc0.w);
      v.z = cvt_pk_bf16(xc1.x, xc1.y);
      v.w = cvt_pk_bf16(xc1.z, xc1.w);
      *(uint4*)(ab + sbyte) = v;
    }
    int nchunk = chunk + 256;
    if (nchunk < (T_LEN * BATCH) / 16) {
      xc0 = *(const float4*)(X + (size_t)(nchunk * 16 + srow) * 256 + sk);
      xc1 = *(const float4*)(X + (size_t)(nchunk * 16 + srow) * 256 + sk + 4);
    }
    soft_barrier();   // stage visible; X prefetch + gi stores stay in flight

    fx4 a00, a10, a01, a11, a02, a12;
#pragma unroll
    for (int j = 0; j < 4; ++j) {
      a00[j] = bias[0][0]; a10[j] = bias[1][0];
      a01[j] = bias[0][1]; a11[j] = bias[1][1];
      a02[j] = bias[0][2]; a12[j] = bias[1][2];
    }

#pragma unroll
    for (int s8 = 0; s8 < 8; ++s8) {
      unsigned aoff = ((unsigned)(col * 512 + (s8 * 32 + kgrp * 8) * 2)) ^
                      ((unsigned)(col & 7) << 4);
      s16x8 af  = *(const s16x8*)(ab + aoff);
      s16x8 w2a = *(const s16x8*)(Wlds + (((wid * 2 + 0) * 8 + s8) * 64 + lane) * 16);
      s16x8 w2b = *(const s16x8*)(Wlds + (((wid * 2 + 1) * 8 + s8) * 64 + lane) * 16);
      a00 = MFMA16(af, wr[0][s8], a00, 0, 0, 0);
      a10 = MFMA16(af, wr[1][s8], a10, 0, 0, 0);
      a01 = MFMA16(af, wr[2][s8], a01, 0, 0, 0);
      a11 = MFMA16(af, wr[3][s8], a11, 0, 0, 0);
      a02 = MFMA16(af, w2a, a02, 0, 0, 0);
      a12 = MFMA16(af, w2b, a12, 0, 0, 0);
    }

    __half* gb = gi + (size_t)chunk * BLK_STRIDE + (unsigned)(wid * 64 + lane) * 8;
    u16x8 o0, o1, o2;
#pragma unroll
    for (int j = 0; j < 4; ++j) {
      o0[j] = __half_as_ushort(__float2half(a00[j]));
      o0[4 + j] = __half_as_ushort(__float2half(a10[j]));
      o1[j] = __half_as_ushort(__float2half(a01[j]));
      o1[4 + j] = __half_as_ushort(__float2half(a11[j]));
      o2[j] = __half_as_ushort(__float2half(a02[j]));
      o2[4 + j] = __half_as_ushort(__float2half(a12[j]));
    }
    *(u16x8*)(gb) = o0;
    *(u16x8*)(gb + GATE_STRIDE) = o1;
    *(u16x8*)(gb + 2 * GATE_STRIDE) = o2;
    parity ^= 1;
  }
}

// ---------------- Kernel B: chunked GRU scan ----------------
__global__ __launch_bounds__(512, 2) void gru_scan_kernel(
    const float* __restrict__ carry, const __half* __restrict__ gi,
    const int* __restrict__ resets, const float* __restrict__ w_hh,
    const float* __restrict__ b_hh, float* __restrict__ out) {
  __shared__ __align__(16) char Wlds[131072];
  __shared__ __align__(16) char Ald[2][8192];   // h bf16 A-tile (sigma K), dbuf
  __shared__ int lastreset[16];

  const int tid = threadIdx.x;
  const int wid = tid >> 6, lane = tid & 63;
  const int col = lane & 15, kgrp = lane >> 4;
  const int bid = blockIdx.x;
  const int bt = bid & 15, c = bid >> 4;
  const int b0 = bt * 16, t0 = c * 32, t1 = t0 + 32;
  const int hid0 = wid * 32 + col;              // wave owns hid0, hid0+16

  s16x8 wr[4][8];
  load_weights<true>(w_hh, wr, Wlds, tid, wid, col, kgrp);
  const float bhhn0 = b_hh[512 + hid0], bhhn1 = b_hh[512 + hid0 + 16];

  // ---- exact scan start: min over batch tile of (last reset < t0) ----
  int s, useCarry;
  if (c == 0) {
    s = 0; useCarry = 1;
  } else {
    if (tid < 16) lastreset[tid] = -1;
    for (int base = t0 - 32;; base -= 32) {
      __syncthreads();
      int tt = base + (tid >> 4);
      if (tt >= 0 && tt < t0) {
        if (resets[tt * BATCH + b0 + (tid & 15)] != 0)
          atomicMax(&lastreset[tid & 15], tt);
      }
      __syncthreads();
      int mn = t0, all = 1;
#pragma unroll
      for (int i = 0; i < 16; ++i) {
        int v = lastreset[i];
        all &= (v >= 0) ? 1 : 0;
        mn = min(mn, v < 0 ? t0 : v);
      }
      if (all) { s = mn; useCarry = 0; break; }
      if (base <= 0) { s = 0; useCarry = 1; break; }
    }
  }

  // ---- init state at t=s into Ald[0] (sigma: pairs (hid,hid+16)) ----
  {
    int row = tid >> 5, k0 = (tid & 31) * 8;
    int tile = k0 >> 5, colb = (k0 >> 1) & 15;
    int rst = resets[s * BATCH + b0 + row];
    float4 va = {0.f, 0.f, 0.f, 0.f}, vb = va;
    if (useCarry && !rst) {
      va = *(const float4*)(carry + (size_t)(b0 + row) * HID + tile * 32 + colb);
      vb = *(const float4*)(carry + (size_t)(b0 + row) * HID + tile * 32 + colb + 16);
    }
    uint4 u;
    u.x = cvt_pk_bf16(va.x, vb.x);
    u.y = cvt_pk_bf16(va.y, vb.y);
    u.z = cvt_pk_bf16(va.z, vb.z);
    u.w = cvt_pk_bf16(va.w, vb.w);
    unsigned byteoff = ((unsigned)(row * 512 + k0 * 2)) ^ ((unsigned)(row & 7) << 4);
    *(uint4*)(Ald[0] + byteoff) = u;
  }
  float hprev[2][4];
#pragma unroll
  for (int ht = 0; ht < 2; ++ht)
#pragma unroll
    for (int j = 0; j < 4; ++j) {
      int b = kgrp * 4 + j;
      int rst = resets[s * BATCH + b0 + b];
      float hv = 0.f;
      if (useCarry && !rst) hv = carry[(size_t)(b0 + b) * HID + hid0 + ht * 16];
      hprev[ht][j] = hv;
    }
  __syncthreads();

  // ---- pipelined scan ----
  const __half* gp = gi + (size_t)(s * 16 + bt) * BLK_STRIDE + (unsigned)(wid * 64 + lane) * 8;
  const int* rbase = resets + b0 + kgrp * 4;
  float* opc = out + 65536 + ((size_t)s * BATCH + b0 + kgrp * 4) * HID + hid0;

  u16x8 gP0 = *(const u16x8*)(gp);
  u16x8 gP1 = *(const u16x8*)(gp + GATE_STRIDE);
  u16x8 gP2 = *(const u16x8*)(gp + 2 * GATE_STRIDE);
  int4 rnC = *(const int4*)(rbase + (size_t)((s + 1 < T_LEN) ? s + 1 : T_LEN - 1) * BATCH);

  for (int t = s; t < t1; ++t) {
    // (1) VMEM loads for t+1 FIRST (retire never waits on later stores)
    const __half* gq = gp + ((t + 1 < t1) ? T_STRIDE : 0u);
    u16x8 gN0 = *(const u16x8*)(gq);
    u16x8 gN1 = *(const u16x8*)(gq + GATE_STRIDE);
    u16x8 gN2 = *(const u16x8*)(gq + 2 * GATE_STRIDE);
    int tn = (t + 2 < T_LEN) ? t + 2 : T_LEN - 1;
    int4 rnN = *(const int4*)(rbase + (size_t)tn * BATCH);

    // (2) acc init via C-in: r,z from gi; n from b_hh
    fx4 a00, a10, a01, a11, a02, a12;
#pragma unroll
    for (int j = 0; j < 4; ++j) {
      a00[j] = __half2float(__ushort_as_half(gP0[j]));
      a10[j] = __half2float(__ushort_as_half(gP0[4 + j]));
      a01[j] = __half2float(__ushort_as_half(gP1[j]));
      a11[j] = __half2float(__ushort_as_half(gP1[4 + j]));
      a02[j] = bhhn0;
      a12[j] = bhhn1;
    }

    // (3) MFMA: 8 af + 16 w2 LDS reads, 48 MFMA
    const char* ab = Ald[(t - s) & 1];
#pragma unroll
    for (int s8 = 0; s8 < 8; ++s8) {
      unsigned aoff = ((unsigned)(col * 512 + (s8 * 32 + kgrp * 8) * 2)) ^
                      ((unsigned)(col & 7) << 4);
      s16x8 af  = *(const s16x8*)(ab + aoff);
      s16x8 w2a = *(const s16x8*)(Wlds + (((wid * 2 + 0) * 8 + s8) * 64 + lane) * 16);
      s16x8 w2b = *(const s16x8*)(Wlds + (((wid * 2 + 1) * 8 + s8) * 64 + lane) * 16);
      a00 = MFMA16(af, wr[0][s8], a00, 0, 0, 0);
      a10 = MFMA16(af, wr[1][s8], a10, 0, 0, 0);
      a01 = MFMA16(af, wr[2][s8], a01, 0, 0, 0);
      a11 = MFMA16(af, wr[3][s8], a11, 0, 0, 0);
      a02 = MFMA16(af, w2a, a02, 0, 0, 0);
      a12 = MFMA16(af, w2b, a12, 0, 0, 0);
    }

    // (4) gates + out stores + h LDS write (paired b32, sigma layout)
    char* aw = (char*)Ald[((t - s) & 1) ^ 1];
    const bool wr_out = (t >= t0);
    const bool lastT = (t + 1 >= T_LEN);
#pragma unroll
    for (int j = 0; j < 4; ++j) {
      int b = kgrp * 4 + j;
      int rj = (j == 0) ? rnC.x : (j == 1) ? rnC.y : (j == 2) ? rnC.z : rnC.w;
      if (lastT) rj = 0;

      float r0 = __builtin_amdgcn_rcpf(1.f + __expf(-a00[j]));
      float z0 = __builtin_amdgcn_rcpf(1.f + __expf(-a01[j]));
      float pn0 = __half2float(__ushort_as_half(gP2[j])) + r0 * a02[j];
      float n0 = 1.f - 2.f * __builtin_amdgcn_rcpf(1.f + __expf(2.f * pn0));
      float h0 = (1.f - z0) * n0 + z0 * hprev[0][j];

      float r1 = __builtin_amdgcn_rcpf(1.f + __expf(-a10[j]));
      float z1 = __builtin_amdgcn_rcpf(1.f + __expf(-a11[j]));
      float pn1 = __half2float(__ushort_as_half(gP2[4 + j])) + r1 * a12[j];
      float n1 = 1.f - 2.f * __builtin_amdgcn_rcpf(1.f + __expf(2.f * pn1));
      float h1 = (1.f - z1) * n1 + z1 * hprev[1][j];

      if (wr_out) {
        __builtin_nontemporal_store(h0, opc + j * HID);
        __builtin_nontemporal_store(h1, opc + j * HID + 16);
      }

      float hk0 = rj ? 0.f : h0;      // pre-apply reset[t+1]
      float hk1 = rj ? 0.f : h1;
      hprev[0][j] = hk0; hprev[1][j] = hk1;

      unsigned hw = cvt_pk_bf16(hk0, hk1);
      unsigned hoff = ((unsigned)(b * 512 + wid * 64 + col * 4)) ^
                      ((unsigned)(b & 7) << 4);
      *(unsigned*)(aw + hoff) = hw;
    }

    gP0 = gN0; gP1 = gN1; gP2 = gN2; rnC = rnN;
    gp = gq;
    opc += 65536;
    soft_barrier();   // lgkm drain only; gi prefetch + out stores in flight
  }

  if (c == 15) {       // h_final = h after t=511 (reset guarded off)
#pragma unroll
    for (int ht = 0; ht < 2; ++ht)
#pragma unroll
      for (int j = 0; j < 4; ++j)
        out[(size_t)(b0 + kgrp * 4 + j) * HID + hid0 + ht * 16] = hprev[ht][j];
  }
}

extern "C" void kernel_launch(void* const* d_in, const int* in_sizes, int n_in,
                              void* d_out, int out_size, void* d_ws, size_t ws_size,
                              hipStream_t stream) {
  const float* carry = (const float*)d_in[0];
  const float* X     = (const float*)d_in[1];
  const int*   rsts  = (const int*)d_in[2];
  const float* w_ih  = (const float*)d_in[3];
  const float* w_hh  = (const float*)d_in[4];
  const float* b_ih  = (const float*)d_in[5];
  const float* b_hh  = (const float*)d_in[6];
  float* out = (float*)d_out;

  const size_t gi_bytes = (size_t)T_LEN * BATCH * 3 * HID * sizeof(__half);  // 192 MiB
  if (ws_size < gi_bytes) return;
  __half* gi = (__half*)d_ws;

  gi_proj_kernel<<<256, 512, 0, stream>>>(X, w_ih, b_ih, b_hh, gi);
  gru_scan_kernel<<<256, 512, 0, stream>>>(carry, gi, rsts, w_hh, b_hh, out);
}